// Round 10
// baseline (254.188 us; speedup 1.0000x reference)
//
#include <hip/hip_runtime.h>
#include <hip/hip_bf16.h>

// MessagePassing: out[dst[e], :] += x[src[e], :]
// x: [N=50000, D=64] fp32; edge_index: [2, E=800000] int32 (src row, dst row)
// Round 9: structural fusion. CSR pipeline (7 dispatches) spent ~60us in
// inter-launch gaps + ~50us building perm. Replace with ONE kernel:
// XCD-binned direct fp32 atomics. Block b handles only dst in range (b&7);
// under round-robin block->XCD dispatch all atomics to an out line come from
// one XCD -> merge in its L2 (1.6MB/range, L2-resident), write back once.
// Per chunk: compact in-range edges to LDS (src|dstLocal packed 16+16),
// then dense processing: 64 lanes/edge, coalesced 256B x-row load + 256B
// atomic row add. Binning is a locality heuristic only; correctness relies
// solely on device-scope atomics + memset-before-kernel.

#define N_NODES_C 50000
#define D_FEAT_C 64
#define NXCD 8
#define NPR ((N_NODES_C + NXCD - 1) / NXCD)   // 6250 nodes per range
#define BLOCK 256
#define EPT 8                                  // edges scanned per thread
#define CHUNK (BLOCK * EPT)                    // 2048 edges per block-iter

static_assert(N_NODES_C < 65536, "src must fit 16 bits");
static_assert(NPR < 65536, "dstLocal must fit 16 bits");

typedef int v4i __attribute__((ext_vector_type(4)));

__global__ void __launch_bounds__(BLOCK) k_fused(const float* __restrict__ x,
                                                 const int* __restrict__ src,
                                                 const int* __restrict__ dst,
                                                 float* __restrict__ out, int E) {
    __shared__ unsigned int s_buf[CHUNK];
    __shared__ int s_cnt;

    const int range = blockIdx.x & (NXCD - 1);
    const int sub   = blockIdx.x >> 3;
    const int nsub  = gridDim.x >> 3;
    const int lo = range * NPR;
    const int hi = lo + NPR;

    const int t = threadIdx.x;
    const int lane = t & 63;
    const int wave = t >> 6;
    const int nchunks = (E + CHUNK - 1) / CHUNK;

    for (int c = sub; c < nchunks; c += nsub) {
        if (t == 0) s_cnt = 0;
        __syncthreads();

        // --- scan phase: 8 edges per thread (2x int4), compact to LDS ---
        const int ebase = c * CHUNK + t * EPT;
        #pragma unroll
        for (int q = 0; q < EPT / 4; ++q) {
            int e0 = ebase + q * 4;
            if (e0 + 3 < E) {
                v4i d = *(const v4i*)(dst + e0);
                v4i s = *(const v4i*)(src + e0);
                if (d.x >= lo && d.x < hi)
                    s_buf[atomicAdd(&s_cnt, 1)] = (unsigned)s.x | ((unsigned)(d.x - lo) << 16);
                if (d.y >= lo && d.y < hi)
                    s_buf[atomicAdd(&s_cnt, 1)] = (unsigned)s.y | ((unsigned)(d.y - lo) << 16);
                if (d.z >= lo && d.z < hi)
                    s_buf[atomicAdd(&s_cnt, 1)] = (unsigned)s.z | ((unsigned)(d.z - lo) << 16);
                if (d.w >= lo && d.w < hi)
                    s_buf[atomicAdd(&s_cnt, 1)] = (unsigned)s.w | ((unsigned)(d.w - lo) << 16);
            } else {
                for (int e = e0; e < E && e < e0 + 4; ++e) {
                    int dd = dst[e];
                    if (dd >= lo && dd < hi)
                        s_buf[atomicAdd(&s_cnt, 1)] = (unsigned)src[e] | ((unsigned)(dd - lo) << 16);
                }
            }
        }
        __syncthreads();
        const int cnt = s_cnt;

        // --- process phase: 64 lanes per edge; 2-way unroll for MLP ---
        int k = wave;
        for (; k + 4 < cnt; k += 8) {
            unsigned p0 = s_buf[k];
            unsigned p1 = s_buf[k + 4];
            float v0 = x[(size_t)(p0 & 0xFFFFu) * D_FEAT_C + lane];
            float v1 = x[(size_t)(p1 & 0xFFFFu) * D_FEAT_C + lane];
            atomicAdd(&out[(size_t)(lo + (p0 >> 16)) * D_FEAT_C + lane], v0);
            atomicAdd(&out[(size_t)(lo + (p1 >> 16)) * D_FEAT_C + lane], v1);
        }
        if (k < cnt) {
            unsigned p0 = s_buf[k];
            float v0 = x[(size_t)(p0 & 0xFFFFu) * D_FEAT_C + lane];
            atomicAdd(&out[(size_t)(lo + (p0 >> 16)) * D_FEAT_C + lane], v0);
        }
        __syncthreads();
    }
}

extern "C" void kernel_launch(void* const* d_in, const int* in_sizes, int n_in,
                              void* d_out, int out_size, void* d_ws, size_t ws_size,
                              hipStream_t stream) {
    const float* x = (const float*)d_in[0];
    const int* edge_index = (const int*)d_in[1];
    float* out = (float*)d_out;

    const int E = in_sizes[1] / 2;            // [2, E] flattened row-major
    const int* src = edge_index;              // edge_index[0]
    const int* dst = edge_index + E;          // edge_index[1]

    // out is poisoned 0xAA before every timed call — zero it (12.8 MB, ~2us).
    (void)hipMemsetAsync(d_out, 0, (size_t)out_size * sizeof(float), stream);

    // 1024 blocks: 128 per node-range; range = blockIdx & 7 aligns with the
    // default round-robin block->XCD assignment (perf heuristic only).
    k_fused<<<1024, BLOCK, 0, stream>>>(x, src, dst, out, E);
}

// Round 11
// 141.023 us; speedup vs baseline: 1.8025x; 1.8025x over previous
//
#include <hip/hip_runtime.h>
#include <hip/hip_bf16.h>

// MessagePassing: out[dst[e], :] += x[src[e], :]
// x: [N=50000, D=64] fp32; edge_index: [2, E=800000] int32 (src row, dst row)
// Round 10: fp32 atomics write through to HBM (WRITE_SIZE == payload, 205 MB)
// -> atomic-bound, refuted. Back to gather, but with a 3-dispatch structure:
//   1. memsetAsync(cnt)            (200 KB)
//   2. k_fill: hist+scatter fused via fixed 64-slot buckets per node
//      (deg ~ Poisson(16); overflow edges -> exact global list, normally 0)
//   3. k_gather: sum min(cnt,64) slots per node (+ overflow scan if cnt>64)
// Removes the 3-kernel scan and ~4 launch gaps (~60us in round 9) and the
// perm build. Fill is XCD-binned (block b only handles dst range b&7) so
// slot-line writes merge in a single XCD's L2.

#define N_NODES_C 50000
#define D_FEAT_C 64
#define NXCD 8
#define NPR ((N_NODES_C + NXCD - 1) / NXCD)   // 6250 nodes per range
#define SLOTS 64
#define OVF_CAP 65536

static_assert(N_NODES_C < 65536, "src/dst must fit 16 bits");

typedef int v4i __attribute__((ext_vector_type(4)));
typedef unsigned short v4u16 __attribute__((ext_vector_type(4)));

__device__ __forceinline__ void fill_one(int d, int s, int* __restrict__ cnt,
                                         unsigned short* __restrict__ slots,
                                         unsigned int* __restrict__ ovf,
                                         int* __restrict__ ovf_cnt) {
    int p = atomicAdd(&cnt[d], 1);
    if (p < SLOTS) {
        slots[(size_t)d * SLOTS + p] = (unsigned short)s;
    } else {
        int i = atomicAdd(ovf_cnt, 1);
        if (i < OVF_CAP) ovf[i] = (unsigned)s | ((unsigned)d << 16);
    }
}

__global__ void __launch_bounds__(256) k_fill(const int* __restrict__ src,
                                              const int* __restrict__ dst,
                                              int* __restrict__ cnt,
                                              unsigned short* __restrict__ slots,
                                              unsigned int* __restrict__ ovf,
                                              int* __restrict__ ovf_cnt, int E) {
    const int range = blockIdx.x & (NXCD - 1);
    const int sub   = blockIdx.x >> 3;
    const int nsub  = gridDim.x >> 3;
    const int lo = range * NPR;
    const int hi = lo + NPR;

    const int n4 = E >> 2;
    const v4i* s4 = (const v4i*)src;
    const v4i* d4 = (const v4i*)dst;
    const int start = sub * blockDim.x + threadIdx.x;
    const int stride = nsub * blockDim.x;

    for (int j = start; j < n4; j += stride) {
        v4i d = d4[j];                       // plain loads: want LLC reuse (8x re-read)
        bool m0 = (d.x >= lo) & (d.x < hi);
        bool m1 = (d.y >= lo) & (d.y < hi);
        bool m2 = (d.z >= lo) & (d.z < hi);
        bool m3 = (d.w >= lo) & (d.w < hi);
        if (m0 | m1 | m2 | m3) {
            v4i s = s4[j];
            if (m0) fill_one(d.x, s.x, cnt, slots, ovf, ovf_cnt);
            if (m1) fill_one(d.y, s.y, cnt, slots, ovf, ovf_cnt);
            if (m2) fill_one(d.z, s.z, cnt, slots, ovf, ovf_cnt);
            if (m3) fill_one(d.w, s.w, cnt, slots, ovf, ovf_cnt);
        }
    }
    for (int j = (n4 << 2) + start; j < E; j += stride) {
        int d = dst[j];
        if (d >= lo && d < hi) fill_one(d, src[j], cnt, slots, ovf, ovf_cnt);
    }
}

// 64 lanes per node, 4 nodes per 256-thread block.
__global__ void __launch_bounds__(256) k_gather2(const float* __restrict__ x,
                                                 const unsigned short* __restrict__ slots,
                                                 const int* __restrict__ cnt,
                                                 const unsigned int* __restrict__ ovf,
                                                 const int* __restrict__ ovf_cnt,
                                                 float* __restrict__ out) {
    int node = blockIdx.x * 4 + (threadIdx.x >> 6);
    int lane = threadIdx.x & 63;
    if (node >= N_NODES_C) return;

    int c = cnt[node];
    int m = c < SLOTS ? c : SLOTS;
    const unsigned short* sl = slots + (size_t)node * SLOTS;

    float a0 = 0.f, a1 = 0.f, a2 = 0.f, a3 = 0.f;
    int k = 0;
    for (; k + 3 < m; k += 4) {              // 8B-aligned broadcast load of 4 slots
        v4u16 q = *(const v4u16*)(sl + k);
        a0 += x[(size_t)q.x * D_FEAT_C + lane];
        a1 += x[(size_t)q.y * D_FEAT_C + lane];
        a2 += x[(size_t)q.z * D_FEAT_C + lane];
        a3 += x[(size_t)q.w * D_FEAT_C + lane];
    }
    for (; k < m; ++k) a0 += x[(size_t)sl[k] * D_FEAT_C + lane];
    float acc = (a0 + a1) + (a2 + a3);

    if (c > SLOTS) {                         // exact overflow path (normally empty)
        int L = *ovf_cnt; if (L > OVF_CAP) L = OVF_CAP;
        for (int i = 0; i < L; ++i) {
            unsigned p = ovf[i];
            if ((int)(p >> 16) == node) acc += x[(size_t)(p & 0xFFFFu) * D_FEAT_C + lane];
        }
    }
    out[(size_t)node * D_FEAT_C + lane] = acc;
}

extern "C" void kernel_launch(void* const* d_in, const int* in_sizes, int n_in,
                              void* d_out, int out_size, void* d_ws, size_t ws_size,
                              hipStream_t stream) {
    const float* x = (const float*)d_in[0];
    const int* edge_index = (const int*)d_in[1];
    float* out = (float*)d_out;

    const int E = in_sizes[1] / 2;            // [2, E] flattened row-major
    const int* src = edge_index;              // edge_index[0]
    const int* dst = edge_index + E;          // edge_index[1]

    // Workspace: cnt[50000] | ovf_cnt | pad | ovf[OVF_CAP] | slots[50000*64] u16
    int* cnt = (int*)d_ws;
    int* ovf_cnt = cnt + N_NODES_C;
    unsigned int* ovf = (unsigned int*)(cnt + N_NODES_C + 4);   // 16B-aligned
    unsigned short* slots = (unsigned short*)(ovf + OVF_CAP);

    // Zero cnt + ovf_cnt in one memset (they're contiguous).
    (void)hipMemsetAsync(cnt, 0, (size_t)(N_NODES_C + 1) * sizeof(int), stream);

    // 1024 blocks: 128 per node-range; range = blockIdx & 7 aligns with
    // round-robin block->XCD dispatch (perf heuristic only).
    k_fill<<<1024, 256, 0, stream>>>(src, dst, cnt, slots, ovf, ovf_cnt, E);

    const int gridN = (N_NODES_C + 3) / 4;    // 4 nodes per block
    k_gather2<<<gridN, 256, 0, stream>>>(x, slots, cnt, ovf, ovf_cnt, out);
}

// Round 12
// 139.801 us; speedup vs baseline: 1.8182x; 1.0087x over previous
//
#include <hip/hip_runtime.h>
#include <hip/hip_bf16.h>

// MessagePassing: out[dst[e], :] += x[src[e], :]
// x: [N=50000, D=64] fp32; edge_index: [2, E=800000] int32 (src row, dst row)
// Round 11 -> 12: keep 3-dispatch slot-bucket structure (memset cnt, k_fill,
// gather). Gather restructured for fat loads: 16-lane float4 groups, 4 edges
// in flight per wave-instruction (16B/lane = coalescing sweet spot), slot
// indices via one 8B broadcast load, cross-group __shfl_xor reduce at end.

#define N_NODES_C 50000
#define D_FEAT_C 64
#define NXCD 8
#define NPR ((N_NODES_C + NXCD - 1) / NXCD)   // 6250 nodes per range
#define SLOTS 64
#define OVF_CAP 65536

static_assert(N_NODES_C < 65536, "src/dst must fit 16 bits");

typedef int v4i __attribute__((ext_vector_type(4)));
typedef float v4f __attribute__((ext_vector_type(4)));

__device__ __forceinline__ void fill_one(int d, int s, int* __restrict__ cnt,
                                         unsigned short* __restrict__ slots,
                                         unsigned int* __restrict__ ovf,
                                         int* __restrict__ ovf_cnt) {
    int p = atomicAdd(&cnt[d], 1);
    if (p < SLOTS) {
        slots[(size_t)d * SLOTS + p] = (unsigned short)s;
    } else {
        int i = atomicAdd(ovf_cnt, 1);
        if (i < OVF_CAP) ovf[i] = (unsigned)s | ((unsigned)d << 16);
    }
}

__global__ void __launch_bounds__(256) k_fill(const int* __restrict__ src,
                                              const int* __restrict__ dst,
                                              int* __restrict__ cnt,
                                              unsigned short* __restrict__ slots,
                                              unsigned int* __restrict__ ovf,
                                              int* __restrict__ ovf_cnt, int E) {
    const int range = blockIdx.x & (NXCD - 1);
    const int sub   = blockIdx.x >> 3;
    const int nsub  = gridDim.x >> 3;
    const int lo = range * NPR;
    const int hi = lo + NPR;

    const int n4 = E >> 2;
    const v4i* s4 = (const v4i*)src;
    const v4i* d4 = (const v4i*)dst;
    const int start = sub * blockDim.x + threadIdx.x;
    const int stride = nsub * blockDim.x;

    for (int j = start; j < n4; j += stride) {
        v4i d = d4[j];                       // plain loads: want LLC reuse (8x re-read)
        bool m0 = (d.x >= lo) & (d.x < hi);
        bool m1 = (d.y >= lo) & (d.y < hi);
        bool m2 = (d.z >= lo) & (d.z < hi);
        bool m3 = (d.w >= lo) & (d.w < hi);
        if (m0 | m1 | m2 | m3) {
            v4i s = s4[j];
            if (m0) fill_one(d.x, s.x, cnt, slots, ovf, ovf_cnt);
            if (m1) fill_one(d.y, s.y, cnt, slots, ovf, ovf_cnt);
            if (m2) fill_one(d.z, s.z, cnt, slots, ovf, ovf_cnt);
            if (m3) fill_one(d.w, s.w, cnt, slots, ovf, ovf_cnt);
        }
    }
    for (int j = (n4 << 2) + start; j < E; j += stride) {
        int d = dst[j];
        if (d >= lo && d < hi) fill_one(d, src[j], cnt, slots, ovf, ovf_cnt);
    }
}

// One node per 64-lane wave; lane = (group g = t>>4, quad q = t&15).
// Per iteration: 4 edges, each 16-lane group loads a float4 (16B/lane).
__global__ void __launch_bounds__(256) k_gather3(const float* __restrict__ x,
                                                 const unsigned short* __restrict__ slots,
                                                 const int* __restrict__ cnt,
                                                 const unsigned int* __restrict__ ovf,
                                                 const int* __restrict__ ovf_cnt,
                                                 float* __restrict__ out) {
    int node = blockIdx.x * 4 + (threadIdx.x >> 6);
    if (node >= N_NODES_C) return;
    const int t = threadIdx.x & 63;
    const int g = t >> 4;                    // edge group 0..3
    const int q = t & 15;                    // feature quad 0..15

    const int c = cnt[node];
    const int m = c < SLOTS ? c : SLOTS;
    const unsigned short* sl = slots + (size_t)node * SLOTS;

    v4f acc = {0.f, 0.f, 0.f, 0.f};
    #pragma unroll 2
    for (int k = 0; k < m; k += 4) {
        // broadcast 8B load of 4 slot ids (slots row is 128B-aligned, k%4==0)
        unsigned long long pk = *(const unsigned long long*)(sl + k);
        int e = k + g;
        if (e < m) {
            int s = (int)((pk >> (16 * g)) & 0xFFFFull);
            v4f v = *(const v4f*)(x + (size_t)s * D_FEAT_C + q * 4);
            acc += v;
        }
    }

    if (c > SLOTS) {                         // exact overflow path (normally empty)
        int L = *ovf_cnt; if (L > OVF_CAP) L = OVF_CAP;
        for (int i = 0; i < L; ++i) {
            unsigned p = ovf[i];
            if ((int)(p >> 16) == node && g == 0) {   // count each edge once
                v4f v = *(const v4f*)(x + (size_t)(p & 0xFFFFu) * D_FEAT_C + q * 4);
                acc += v;
            }
        }
    }

    // reduce the 4 edge-groups: xor 16 then 32 -> every lane has the full sum
    #pragma unroll
    for (int off = 16; off <= 32; off <<= 1) {
        acc.x += __shfl_xor(acc.x, off, 64);
        acc.y += __shfl_xor(acc.y, off, 64);
        acc.z += __shfl_xor(acc.z, off, 64);
        acc.w += __shfl_xor(acc.w, off, 64);
    }
    if (g == 0) *(v4f*)(out + (size_t)node * D_FEAT_C + q * 4) = acc;
}

extern "C" void kernel_launch(void* const* d_in, const int* in_sizes, int n_in,
                              void* d_out, int out_size, void* d_ws, size_t ws_size,
                              hipStream_t stream) {
    const float* x = (const float*)d_in[0];
    const int* edge_index = (const int*)d_in[1];
    float* out = (float*)d_out;

    const int E = in_sizes[1] / 2;            // [2, E] flattened row-major
    const int* src = edge_index;              // edge_index[0]
    const int* dst = edge_index + E;          // edge_index[1]

    // Workspace: cnt[50000] | ovf_cnt | pad | ovf[OVF_CAP] | slots[50000*64] u16
    int* cnt = (int*)d_ws;
    int* ovf_cnt = cnt + N_NODES_C;
    unsigned int* ovf = (unsigned int*)(cnt + N_NODES_C + 4);   // 16B-aligned
    unsigned short* slots = (unsigned short*)(ovf + OVF_CAP);

    (void)hipMemsetAsync(cnt, 0, (size_t)(N_NODES_C + 1) * sizeof(int), stream);

    // 1024 blocks: 128 per node-range; range = blockIdx & 7 aligns with
    // round-robin block->XCD dispatch (perf heuristic only).
    k_fill<<<1024, 256, 0, stream>>>(src, dst, cnt, slots, ovf, ovf_cnt, E);

    const int gridN = (N_NODES_C + 3) / 4;    // 4 nodes (4 waves) per block
    k_gather3<<<gridN, 256, 0, stream>>>(x, slots, cnt, ovf, ovf_cnt, out);
}